// Round 3
// baseline (2966.873 us; speedup 1.0000x reference)
//
#include <hip/hip_runtime.h>
#include <math.h>

#define B_ 16
#define L_ 256
#define S_ 100
#define LA_ 48
#define NA_ 32
#define E_ 64
#define D_ 768
#define H_ 12
#define NHID_ 1024
#define WIDX_ 102
#define EPSF 1e-12f

// ---------------- meta: per-b sb, sls, last ----------------
__global__ void k_meta(const int* __restrict__ idxs, const int* __restrict__ blen,
                       int* __restrict__ meta) {
  int b = blockIdx.x, t = threadIdx.x;
  __shared__ int cnt;
  if (t == 0) cnt = 0;
  __syncthreads();
  if (t < WIDX_ && idxs[b * WIDX_ + t] > 0) atomicAdd(&cnt, 1);
  __syncthreads();
  if (t == 0) {
    int sb = cnt - 2;
    meta[b * 4 + 0] = sb;
    meta[b * 4 + 1] = idxs[b * WIDX_ + sb];  // sls
    meta[b * 4 + 2] = blen[b] - 1;           // last
  }
}

// ---------------- gather sent_emb (y<S) and arg_emb (y>=S) ----------------
__global__ void k_gather(const float* __restrict__ emb, const int* __restrict__ idxs,
                         const int* __restrict__ meta, float* __restrict__ sent_emb,
                         float* __restrict__ arg_emb) {
  int b = blockIdx.y, y = blockIdx.x, t = threadIdx.x;
  int sb = meta[b * 4 + 0], sls = meta[b * 4 + 1], last = meta[b * 4 + 2];
  if (y < S_) {
    int s = y;
    float* dst = sent_emb + ((size_t)b * S_ + s) * D_;
    if (s < sb) {
      const float* src = emb + ((size_t)b * L_ + idxs[b * WIDX_ + s]) * D_;
      for (int d = t; d < D_; d += 256) dst[d] = src[d];
    } else {
      for (int d = t; d < D_; d += 256) dst[d] = 0.f;
    }
  } else {
    int l = y - S_;
    int pos = sls + 1 + l;
    float* dst = arg_emb + ((size_t)b * LA_ + l) * D_;
    if (pos < last) {
      int p = pos > (L_ - 1) ? (L_ - 1) : pos;
      const float* src = emb + ((size_t)b * L_ + p) * D_;
      for (int d = t; d < D_; d += 256) dst[d] = src[d];
    } else {
      for (int d = t; d < D_; d += 256) dst[d] = 0.f;
    }
  }
}

// ---------------- trig: weighted mean over triggers ----------------
__global__ void k_trig(const float* __restrict__ sent_emb, const float* __restrict__ is_trig,
                       float* __restrict__ trig) {
  int b = blockIdx.y;
  int d = blockIdx.x * 256 + threadIdx.x;
  float acc = 0.f, den = 0.f;
  for (int s = 0; s < S_; s++) {
    float w = is_trig[b * S_ + s];
    den += w;
    if (w != 0.f) acc += w * sent_emb[((size_t)b * S_ + s) * D_ + d];
  }
  trig[b * D_ + d] = acc / den;
}

// ---------------- entity0 = ent_map^T @ sent_emb ; also e0*trig and nonempty ----------------
__global__ __launch_bounds__(256) void k_entity0(const float* __restrict__ sent_emb,
                                                 const float* __restrict__ ent_map,
                                                 const float* __restrict__ trig,
                                                 float* __restrict__ e0, float* __restrict__ e0t,
                                                 float* __restrict__ ne) {
  int b = blockIdx.y, e = blockIdx.x, t = threadIdx.x;
  float a0 = 0.f, a1 = 0.f, a2 = 0.f;
  for (int s = 0; s < S_; s++) {
    float w = ent_map[((size_t)b * S_ + s) * E_ + e];
    if (w != 0.f) {
      const float* r = sent_emb + ((size_t)b * S_ + s) * D_;
      a0 += w * r[t]; a1 += w * r[t + 256]; a2 += w * r[t + 512];
    }
  }
  size_t o = ((size_t)b * E_ + e) * D_;
  e0[o + t] = a0; e0[o + t + 256] = a1; e0[o + t + 512] = a2;
  const float* tr = trig + b * D_;
  e0t[o + t] = a0 * tr[t];
  e0t[o + t + 256] = a1 * tr[t + 256];
  e0t[o + t + 512] = a2 * tr[t + 512];
  __shared__ float red[256];
  red[t] = fabsf(a0) + fabsf(a1) + fabsf(a2);
  __syncthreads();
  for (int s2 = 128; s2 > 0; s2 >>= 1) {
    if (t < s2) red[t] += red[t + s2];
    __syncthreads();
  }
  if (t == 0) ne[b * E_ + e] = (red[0] > 0.f) ? 1.f : 0.f;
}

// ---------------- generic weighted sum: O[b,x,:] = sum_y W[b, y*sy + x*sx] * V[b,y,:] ----------------
__global__ __launch_bounds__(256) void k_wsum(const float* __restrict__ Wm, int wstride, int sy,
                                              int sx, const float* __restrict__ Vm,
                                              float* __restrict__ Om, int Y) {
  int b = blockIdx.y, x = blockIdx.x, t = threadIdx.x;
  float a0 = 0.f, a1 = 0.f, a2 = 0.f;
  const float* wb = Wm + (size_t)b * wstride + (size_t)x * sx;
  const float* vb = Vm + (size_t)b * Y * D_;
  for (int y = 0; y < Y; y++) {
    float w = wb[(size_t)y * sy];
    if (w != 0.f) {
      const float* r = vb + (size_t)y * D_;
      a0 += w * r[t]; a1 += w * r[t + 256]; a2 += w * r[t + 512];
    }
  }
  float* o = Om + ((size_t)b * gridDim.x + x) * D_;
  o[t] = a0; o[t + 256] = a1; o[t + 512] = a2;
}

// ---------------- tb[b,d] = b_ta[d] + sum_k trig[b,k]*W_ta[(D+k)*D + d] ----------------
__global__ void k_tb(const float* __restrict__ trig, const float* __restrict__ W_ta,
                     const float* __restrict__ b_ta, float* __restrict__ tb) {
  int b = blockIdx.y;
  int d = blockIdx.x * 256 + threadIdx.x;
  float acc = b_ta[d];
  for (int k = 0; k < D_; k++) acc += trig[b * D_ + k] * W_ta[(size_t)(D_ + k) * D_ + d];
  tb[b * D_ + d] = acc;
}

// ---------------- uber-GEMM: job table, 64x128 tile, in-block multi-pair K-fusion ----------------
// C_j[M,N] = sum_p A_j_p[M,768] @ B_j_p[768,N].  All pairs have K=768 (48 iters of BK=16).
// No atomics: every block owns its C tile exclusively.
#define MAXJ 4
struct GJobs {
  const float* A[MAXJ * 3];
  const float* Bw[MAXJ * 3];
  float* C[MAXJ];
  int N[MAXJ], ntile[MAXJ], niter[MAXJ];  // niter = npairs*48
  int tstart[MAXJ + 1];
  int njobs;
};

__global__ __launch_bounds__(256, 4) void k_gemmx(GJobs J) {
  __shared__ float As[2][16][68];
  __shared__ float BsL[2][16][68];
  __shared__ float BsH[2][16][68];
  int bx = blockIdx.x;
  int j = 0;
  while (j < J.njobs - 1 && bx >= J.tstart[j + 1]) j++;
  int local = bx - J.tstart[j];
  int nt = J.ntile[j];
  int by = local / nt;
  int bn0 = (local - by * nt) * 128;
  int N = J.N[j];
  int tid = threadIdx.x;
  int am = tid >> 2, ak = (tid & 3) << 2;
  int bk = tid >> 4, bn = (tid & 15) << 2;
  int niter = J.niter[j];

  // flattened K across pairs: it -> pair p = it/48, kk = it%48
  const float* A0 = J.A[j * 3 + 0];
  const float* A1 = J.A[j * 3 + 1];
  const float* A2 = J.A[j * 3 + 2];
  const float* B0 = J.Bw[j * 3 + 0];
  const float* B1 = J.Bw[j * 3 + 1];
  const float* B2 = J.Bw[j * 3 + 2];

  // first tile (it=0 -> pair 0, kk 0)
  float4 av = *(const float4*)(A0 + (size_t)(by * 64 + am) * D_ + ak);
  const float* b0p = B0 + (size_t)bk * N + bn0 + bn;
  float4 bL = *(const float4*)b0p;
  float4 bH = *(const float4*)(b0p + 64);
  As[0][ak + 0][am] = av.x; As[0][ak + 1][am] = av.y;
  As[0][ak + 2][am] = av.z; As[0][ak + 3][am] = av.w;
  *(float4*)&BsL[0][bk][bn] = bL;
  *(float4*)&BsH[0][bk][bn] = bH;

  float acc[4][8] = {};
  int tx = tid & 15, ty = tid >> 4;
  int buf = 0;
  for (int it = 0; it < niter; ++it) {
    __syncthreads();
    bool more = (it + 1 < niter);
    if (more) {
      int l = it + 1;
      int p2 = (l >= 96) ? 2 : ((l >= 48) ? 1 : 0);
      int kk = l - p2 * 48;
      const float* Ap = (p2 == 0) ? A0 : ((p2 == 1) ? A1 : A2);
      const float* Bp = (p2 == 0) ? B0 : ((p2 == 1) ? B1 : B2);
      av = *(const float4*)(Ap + (size_t)(by * 64 + am) * D_ + kk * 16 + ak);
      const float* bp = Bp + (size_t)(kk * 16 + bk) * N + bn0 + bn;
      bL = *(const float4*)bp;
      bH = *(const float4*)(bp + 64);
    }
#define FMAROW(i, as)                                                      \
  acc[i][0] += (as)*bl.x; acc[i][1] += (as)*bl.y; acc[i][2] += (as)*bl.z;  \
  acc[i][3] += (as)*bl.w; acc[i][4] += (as)*bh.x; acc[i][5] += (as)*bh.y;  \
  acc[i][6] += (as)*bh.z; acc[i][7] += (as)*bh.w;
#pragma unroll
    for (int k = 0; k < 16; ++k) {
      float4 a4 = *(const float4*)&As[buf][k][ty * 4];
      float4 bl = *(const float4*)&BsL[buf][k][tx * 4];
      float4 bh = *(const float4*)&BsH[buf][k][tx * 4];
      FMAROW(0, a4.x) FMAROW(1, a4.y) FMAROW(2, a4.z) FMAROW(3, a4.w)
    }
    if (more) {
      buf ^= 1;
      As[buf][ak + 0][am] = av.x; As[buf][ak + 1][am] = av.y;
      As[buf][ak + 2][am] = av.z; As[buf][ak + 3][am] = av.w;
      *(float4*)&BsL[buf][bk][bn] = bL;
      *(float4*)&BsH[buf][bk][bn] = bH;
    }
  }
  float* Cj = J.C[j];
#pragma unroll
  for (int i = 0; i < 4; ++i) {
    int row = by * 64 + ty * 4 + i;
    float* cr = Cj + (size_t)row * N + bn0;
    *(float4*)(cr + tx * 4) = make_float4(acc[i][0], acc[i][1], acc[i][2], acc[i][3]);
    *(float4*)(cr + 64 + tx * 4) = make_float4(acc[i][4], acc[i][5], acc[i][6], acc[i][7]);
  }
}

// ---------------- entity_new epilogue: (C + tb[b]) * nonempty ----------------
__global__ void k_entnew_ep(float* __restrict__ C, const float* __restrict__ tb,
                            const float* __restrict__ ne) {
  int r = blockIdx.x, t = threadIdx.x;
  int b = r >> 6;
  float m = ne[r];
  size_t o = (size_t)r * D_;
  for (int d = t; d < D_; d += 256) C[o + d] = (C[o + d] + tb[b * D_ + d]) * m;
}

// ---------------- score[b,e,a] = dot(entity_new[b,e], arg[b,a]) / sqrt(D) ----------------
__global__ __launch_bounds__(256) void k_score(const float* __restrict__ entn,
                                               const float* __restrict__ argm,
                                               float* __restrict__ score) {
  int b = blockIdx.y, e = blockIdx.x, t = threadIdx.x;
  __shared__ float ent[D_];
  const float* er = entn + ((size_t)b * E_ + e) * D_;
  for (int d = t; d < D_; d += 256) ent[d] = er[d];
  __syncthreads();
  int wave = t >> 6, lane = t & 63;
  const float scale = 0.03608439182435161f;  // 1/sqrt(768)
  for (int a = wave; a < NA_; a += 4) {
    const float* ar = argm + ((size_t)b * NA_ + a) * D_;
    float p = 0.f;
#pragma unroll
    for (int i = 0; i < 12; i++) {
      int d = lane + 64 * i;
      p += ent[d] * ar[d];
    }
    for (int off = 32; off > 0; off >>= 1) p += __shfl_down(p, off);
    if (lane == 0) score[((size_t)b * E_ + e) * NA_ + a] = p * scale;
  }
}

// ---------------- L1 normalize over a (t2a) and over e (a2t) ----------------
__global__ void k_norm(const float* __restrict__ score, float* __restrict__ t2a,
                       float* __restrict__ a2t) {
  int b = blockIdx.x, t = threadIdx.x;
  __shared__ float s[E_ * NA_];
  __shared__ float rs[E_];
  __shared__ float cs[NA_];
  for (int i = t; i < E_ * NA_; i += 256) s[i] = score[(size_t)b * E_ * NA_ + i];
  __syncthreads();
  if (t < E_) {
    float sum = 0.f;
    for (int a = 0; a < NA_; a++) sum += fabsf(s[t * NA_ + a]);
    rs[t] = fmaxf(sum, EPSF);
  } else if (t >= 64 && t < 96) {
    int a = t - 64;
    float sum = 0.f;
    for (int e = 0; e < E_; e++) sum += fabsf(s[e * NA_ + a]);
    cs[a] = fmaxf(sum, EPSF);
  }
  __syncthreads();
  for (int i = t; i < E_ * NA_; i += 256) {
    int e = i >> 5, a = i & 31;
    float v = s[i];
    t2a[(size_t)b * E_ * NA_ + i] = v / rs[e];
    a2t[(size_t)b * E_ * NA_ + i] = v / cs[a];
  }
}

// ---------------- a2a = softmax(arg @ arg^T) ----------------
__global__ __launch_bounds__(256) void k_a2a(const float* __restrict__ argm,
                                             float* __restrict__ a2a) {
  int b = blockIdx.y, a = blockIdx.x, t = threadIdx.x;
  __shared__ float sA[D_];
  __shared__ float lg[NA_];
  const float* ar = argm + ((size_t)b * NA_ + a) * D_;
  for (int d = t; d < D_; d += 256) sA[d] = ar[d];
  __syncthreads();
  int wave = t >> 6, lane = t & 63;
  for (int a2 = wave; a2 < NA_; a2 += 4) {
    const float* br = argm + ((size_t)b * NA_ + a2) * D_;
    float p = 0.f;
#pragma unroll
    for (int i = 0; i < 12; i++) {
      int d = lane + 64 * i;
      p += sA[d] * br[d];
    }
    for (int off = 32; off > 0; off >>= 1) p += __shfl_down(p, off);
    if (lane == 0) lg[a2] = p;
  }
  __syncthreads();
  if (t < 64) {
    float v = (t < NA_) ? lg[t] : -INFINITY;
    float m = v;
    for (int mask = 16; mask > 0; mask >>= 1) m = fmaxf(m, __shfl_xor(m, mask));
    float ex = (t < NA_) ? expf(v - m) : 0.f;
    float sm = ex;
    for (int mask = 16; mask > 0; mask >>= 1) sm += __shfl_xor(sm, mask);
    if (t < NA_) a2a[((size_t)b * NA_ + a) * NA_ + t] = ex / sm;
  }
}

// ---------------- t2t: gathered, head-mean, per-att row-normalized, averaged ----------------
__global__ __launch_bounds__(128) void k_t2t(const float* __restrict__ att0,
                                             const float* __restrict__ att1,
                                             const float* __restrict__ att2,
                                             const int* __restrict__ idxs,
                                             const int* __restrict__ meta,
                                             float* __restrict__ t2t) {
  int b = blockIdx.y, s = blockIdx.x, t = threadIdx.x;
  int sb = meta[b * 4 + 0];
  float* out = t2t + ((size_t)b * S_ + s) * S_;
  if (s >= sb) {
    for (int j = t; j < S_; j += 128) out[j] = 0.f;
    return;
  }
  int Is = idxs[b * WIDX_ + s];
  int It = (t < S_) ? idxs[b * WIDX_ + t] : 0;
  __shared__ float row[256];
  __shared__ float red[128];
  const float* atts[3] = {att0, att1, att2};
  float accout = 0.f;
  for (int q = 0; q < 3; q++) {
    float r0 = 0.f, r1 = 0.f;
    const float* base = atts[q] + (((size_t)b * H_) * L_ + Is) * L_;
    for (int h = 0; h < H_; h++) {
      const float* rp = base + (size_t)h * L_ * L_;
      r0 += rp[t];
      r1 += rp[t + 128];
    }
    row[t] = r0;
    row[t + 128] = r1;
    __syncthreads();
    float v = (t < sb) ? row[It] * (1.f / 12.f) : 0.f;
    red[t] = v;
    __syncthreads();
    for (int s2 = 64; s2 > 0; s2 >>= 1) {
      if (t < s2) red[t] += red[t + s2];
      __syncthreads();
    }
    float rsum = red[0];
    __syncthreads();
    accout += v / fmaxf(rsum, EPSF) * (1.f / 3.f);
  }
  if (t < S_) out[t] = accout;
}

// ---------------- final: out = gelu(Pe_ab+Pe_c + Pa_ab+Pa_c + b1) @ W2 + b2 ----------------
__global__ __launch_bounds__(256) void k_final(const float* __restrict__ PeA,
                                               const float* __restrict__ PeC,
                                               const float* __restrict__ PaA,
                                               const float* __restrict__ PaC,
                                               const float* __restrict__ b1,
                                               const float* __restrict__ W2,
                                               const float* __restrict__ b2,
                                               float* __restrict__ out) {
  int b = blockIdx.y, e = blockIdx.x, t = threadIdx.x;
  __shared__ float pe[NHID_];
  size_t po = ((size_t)b * E_ + e) * NHID_;
  for (int n = t; n < NHID_; n += 256) pe[n] = PeA[po + n] + PeC[po + n] + b1[n];
  __syncthreads();
  int a = t >> 3, c = t & 7;
  size_t ao = ((size_t)b * NA_ + a) * NHID_;
  const float* parA = PaA + ao;
  const float* parC = PaC + ao;
  float acc = 0.f;
#pragma unroll 4
  for (int jj = 0; jj < 128; ++jj) {
    int n = c * 128 + jj;
    float x = pe[n] + parA[n] + parC[n];
    float g = 0.5f * x * (1.f + erff(x * 0.70710678118654752f));
    acc += g * W2[n];
  }
  acc += __shfl_down(acc, 4);
  acc += __shfl_down(acc, 2);
  acc += __shfl_down(acc, 1);
  if (c == 0) out[((size_t)b * E_ + e) * NA_ + a] = acc + b2[0];
}

extern "C" void kernel_launch(void* const* d_in, const int* in_sizes, int n_in,
                              void* d_out, int out_size, void* d_ws, size_t ws_size,
                              hipStream_t stream) {
  const float* emb    = (const float*)d_in[0];
  const float* istrig = (const float*)d_in[1];
  const float* argw   = (const float*)d_in[2];
  const float* entmap = (const float*)d_in[3];
  const float* att0   = (const float*)d_in[4];
  const float* att1   = (const float*)d_in[5];
  const float* att2   = (const float*)d_in[6];
  const float* W_ta   = (const float*)d_in[7];
  const float* b_ta   = (const float*)d_in[8];
  const float* W1     = (const float*)d_in[9];
  const float* b1     = (const float*)d_in[10];
  const float* W2     = (const float*)d_in[11];
  const float* b2     = (const float*)d_in[12];
  const int*   idxs   = (const int*)d_in[13];
  const int*   blen   = (const int*)d_in[14];
  float* out = (float*)d_out;

  float* ws = (float*)d_ws;
  size_t o = 0;
  int* meta = (int*)ws; o += 256;
  float* sent_emb = ws + o; o += (size_t)B_ * S_ * D_;   // dead after phase A -> reused as PeC
  float* arg_emb  = ws + o; o += (size_t)B_ * LA_ * D_;  // dead after argm  -> reused as PaC
  float* trig     = ws + o; o += (size_t)B_ * D_;
  float* e0       = ws + o; o += (size_t)B_ * E_ * D_;
  float* e0t      = ws + o; o += (size_t)B_ * E_ * D_;
  float* argm     = ws + o; o += (size_t)B_ * NA_ * D_;
  float* entn     = ws + o; o += (size_t)B_ * E_ * D_;
  float* tb       = ws + o; o += (size_t)B_ * D_;
  float* ne       = ws + o; o += (size_t)B_ * E_;
  float* score    = ws + o; o += (size_t)B_ * E_ * NA_;
  float* t2a      = ws + o; o += (size_t)B_ * E_ * NA_;
  float* a2t      = ws + o; o += (size_t)B_ * E_ * NA_;
  float* t2t      = ws + o; o += (size_t)B_ * S_ * S_;
  float* ah2h     = ws + o; o += (size_t)B_ * S_ * D_;
  float* Ah2h     = ws + o; o += (size_t)B_ * E_ * D_;
  float* tokA     = ws + o; o += (size_t)B_ * E_ * D_;
  float* argTok   = ws + o; o += (size_t)B_ * NA_ * D_;
  float* a2a      = ws + o; o += (size_t)B_ * NA_ * NA_;
  float* Au2u     = ws + o; o += (size_t)B_ * NA_ * D_;
  float* PeA      = ws + o; o += (size_t)B_ * E_ * NHID_;
  float* PaA      = ws + o; o += (size_t)B_ * NA_ * NHID_;
  // phase-D outputs overlap buffers that are dead by then:
  float* PeC = sent_emb;  // 1.05M floats <= 1.23M
  float* PaC = arg_emb;   // 0.52M floats <= 0.59M

  // ---- phase A: gathers + everything not depending on entity_new ----
  k_meta<<<B_, 128, 0, stream>>>(idxs, blen, meta);
  k_gather<<<dim3(S_ + LA_, B_), 256, 0, stream>>>(emb, idxs, meta, sent_emb, arg_emb);
  k_trig<<<dim3(3, B_), 256, 0, stream>>>(sent_emb, istrig, trig);
  k_entity0<<<dim3(E_, B_), 256, 0, stream>>>(sent_emb, entmap, trig, e0, e0t, ne);
  k_wsum<<<dim3(NA_, B_), 256, 0, stream>>>(argw, LA_ * NA_, NA_, 1, arg_emb, argm, LA_);
  k_tb<<<dim3(3, B_), 256, 0, stream>>>(trig, W_ta, b_ta, tb);
  k_t2t<<<dim3(S_, B_), 128, 0, stream>>>(att0, att1, att2, idxs, meta, t2t);
  k_wsum<<<dim3(S_, B_), 256, 0, stream>>>(t2t, S_ * S_, 1, S_, sent_emb, ah2h, S_);
  k_wsum<<<dim3(E_, B_), 256, 0, stream>>>(entmap, S_ * E_, E_, 1, ah2h, Ah2h, S_);
  k_a2a<<<dim3(NA_, B_), 256, 0, stream>>>(argm, a2a);
  k_wsum<<<dim3(NA_, B_), 256, 0, stream>>>(a2a, NA_ * NA_, 1, NA_, argm, Au2u, NA_);

  // ---- phase B: entn (2 pairs), PeA (2 pairs), PaA (2 pairs) — 288 blocks ----
  GJobs JB = {};
  {
    int jn = 0, tt = 0;
    auto add = [&](const float* a0, const float* w0, const float* a1, const float* w1,
                   const float* a2, const float* w2, float* C, int N, int mt, int npairs) {
      JB.A[jn * 3 + 0] = a0; JB.Bw[jn * 3 + 0] = w0;
      JB.A[jn * 3 + 1] = a1; JB.Bw[jn * 3 + 1] = w1;
      JB.A[jn * 3 + 2] = a2; JB.Bw[jn * 3 + 2] = w2;
      JB.C[jn] = C; JB.N[jn] = N; JB.ntile[jn] = N / 128;
      JB.niter[jn] = npairs * 48;
      JB.tstart[jn] = tt; tt += mt * (N / 128); jn++;
    };
    add(e0, W_ta, e0t, W_ta + (size_t)2 * D_ * D_, e0, W_ta, entn, D_, 16, 2);
    add(e0, W1, Ah2h, W1 + (size_t)3 * D_ * NHID_, e0, W1, PeA, NHID_, 16, 2);
    add(argm, W1 + (size_t)D_ * NHID_, Au2u, W1 + (size_t)5 * D_ * NHID_, argm, W1, PaA,
        NHID_, 8, 2);
    JB.njobs = jn; JB.tstart[jn] = tt;
    k_gemmx<<<tt, 256, 0, stream>>>(JB);
  }

  // ---- phase C: entity_new epilogue + score path ----
  k_entnew_ep<<<B_ * E_, 256, 0, stream>>>(entn, tb, ne);
  k_score<<<dim3(E_, B_), 256, 0, stream>>>(entn, argm, score);
  k_norm<<<B_, 256, 0, stream>>>(score, t2a, a2t);
  k_wsum<<<dim3(E_, B_), 256, 0, stream>>>(t2a, E_ * NA_, 1, NA_, argm, tokA, NA_);
  k_wsum<<<dim3(NA_, B_), 256, 0, stream>>>(a2t, E_ * NA_, NA_, 1, entn, argTok, E_);

  // ---- phase D: PeC (tokA), PaC (argTok) — 192 blocks ----
  GJobs JD = {};
  {
    int jn = 0, tt = 0;
    auto add = [&](const float* a0, const float* w0, float* C, int N, int mt) {
      JD.A[jn * 3 + 0] = a0; JD.Bw[jn * 3 + 0] = w0;
      JD.A[jn * 3 + 1] = a0; JD.Bw[jn * 3 + 1] = w0;
      JD.A[jn * 3 + 2] = a0; JD.Bw[jn * 3 + 2] = w0;
      JD.C[jn] = C; JD.N[jn] = N; JD.ntile[jn] = N / 128;
      JD.niter[jn] = 48;
      JD.tstart[jn] = tt; tt += mt * (N / 128); jn++;
    };
    add(tokA, W1 + (size_t)2 * D_ * NHID_, PeC, NHID_, 16);
    add(argTok, W1 + (size_t)4 * D_ * NHID_, PaC, NHID_, 8);
    JD.njobs = jn; JD.tstart[jn] = tt;
    k_gemmx<<<tt, 256, 0, stream>>>(JD);
  }

  // ---- final ----
  k_final<<<dim3(E_, B_), 256, 0, stream>>>(PeA, PeC, PaA, PaC, b1, W2, b2, out);
}

// Round 4
// 905.980 us; speedup vs baseline: 3.2748x; 3.2748x over previous
//
#include <hip/hip_runtime.h>
#include <math.h>

#define B_ 16
#define L_ 256
#define S_ 100
#define LA_ 48
#define NA_ 32
#define E_ 64
#define D_ 768
#define H_ 12
#define NHID_ 1024
#define WIDX_ 102
#define EPSF 1e-12f

// ---------------- meta: per-b sb, sls, last ----------------
__global__ void k_meta(const int* __restrict__ idxs, const int* __restrict__ blen,
                       int* __restrict__ meta) {
  int b = blockIdx.x, t = threadIdx.x;
  __shared__ int cnt;
  if (t == 0) cnt = 0;
  __syncthreads();
  if (t < WIDX_ && idxs[b * WIDX_ + t] > 0) atomicAdd(&cnt, 1);
  __syncthreads();
  if (t == 0) {
    int sb = cnt - 2;
    meta[b * 4 + 0] = sb;
    meta[b * 4 + 1] = idxs[b * WIDX_ + sb];  // sls
    meta[b * 4 + 2] = blen[b] - 1;           // last
  }
}

// ---------------- gather sent_emb (y<S) and arg_emb (y>=S) ----------------
__global__ void k_gather(const float* __restrict__ emb, const int* __restrict__ idxs,
                         const int* __restrict__ meta, float* __restrict__ sent_emb,
                         float* __restrict__ arg_emb) {
  int b = blockIdx.y, y = blockIdx.x, t = threadIdx.x;
  int sb = meta[b * 4 + 0], sls = meta[b * 4 + 1], last = meta[b * 4 + 2];
  if (y < S_) {
    int s = y;
    float* dst = sent_emb + ((size_t)b * S_ + s) * D_;
    if (s < sb) {
      const float* src = emb + ((size_t)b * L_ + idxs[b * WIDX_ + s]) * D_;
      for (int d = t; d < D_; d += 256) dst[d] = src[d];
    } else {
      for (int d = t; d < D_; d += 256) dst[d] = 0.f;
    }
  } else {
    int l = y - S_;
    int pos = sls + 1 + l;
    float* dst = arg_emb + ((size_t)b * LA_ + l) * D_;
    if (pos < last) {
      int p = pos > (L_ - 1) ? (L_ - 1) : pos;
      const float* src = emb + ((size_t)b * L_ + p) * D_;
      for (int d = t; d < D_; d += 256) dst[d] = src[d];
    } else {
      for (int d = t; d < D_; d += 256) dst[d] = 0.f;
    }
  }
}

// ---------------- trig: weighted mean over triggers ----------------
__global__ void k_trig(const float* __restrict__ sent_emb, const float* __restrict__ is_trig,
                       float* __restrict__ trig) {
  int b = blockIdx.y;
  int d = blockIdx.x * 256 + threadIdx.x;
  float acc = 0.f, den = 0.f;
  for (int s = 0; s < S_; s++) {
    float w = is_trig[b * S_ + s];
    den += w;
    if (w != 0.f) acc += w * sent_emb[((size_t)b * S_ + s) * D_ + d];
  }
  trig[b * D_ + d] = acc / den;
}

// ---------------- entity0 = ent_map^T @ sent_emb ; also e0*trig and nonempty ----------------
__global__ __launch_bounds__(256) void k_entity0(const float* __restrict__ sent_emb,
                                                 const float* __restrict__ ent_map,
                                                 const float* __restrict__ trig,
                                                 float* __restrict__ e0, float* __restrict__ e0t,
                                                 float* __restrict__ ne) {
  int b = blockIdx.y, e = blockIdx.x, t = threadIdx.x;
  float a0 = 0.f, a1 = 0.f, a2 = 0.f;
  for (int s = 0; s < S_; s++) {
    float w = ent_map[((size_t)b * S_ + s) * E_ + e];
    if (w != 0.f) {
      const float* r = sent_emb + ((size_t)b * S_ + s) * D_;
      a0 += w * r[t]; a1 += w * r[t + 256]; a2 += w * r[t + 512];
    }
  }
  size_t o = ((size_t)b * E_ + e) * D_;
  e0[o + t] = a0; e0[o + t + 256] = a1; e0[o + t + 512] = a2;
  const float* tr = trig + b * D_;
  e0t[o + t] = a0 * tr[t];
  e0t[o + t + 256] = a1 * tr[t + 256];
  e0t[o + t + 512] = a2 * tr[t + 512];
  __shared__ float red[256];
  red[t] = fabsf(a0) + fabsf(a1) + fabsf(a2);
  __syncthreads();
  for (int s2 = 128; s2 > 0; s2 >>= 1) {
    if (t < s2) red[t] += red[t + s2];
    __syncthreads();
  }
  if (t == 0) ne[b * E_ + e] = (red[0] > 0.f) ? 1.f : 0.f;
}

// ---------------- generic weighted sum: O[b,x,:] = sum_y W[b, y*sy + x*sx] * V[b,y,:] ----------------
__global__ __launch_bounds__(256) void k_wsum(const float* __restrict__ Wm, int wstride, int sy,
                                              int sx, const float* __restrict__ Vm,
                                              float* __restrict__ Om, int Y) {
  int b = blockIdx.y, x = blockIdx.x, t = threadIdx.x;
  float a0 = 0.f, a1 = 0.f, a2 = 0.f;
  const float* wb = Wm + (size_t)b * wstride + (size_t)x * sx;
  const float* vb = Vm + (size_t)b * Y * D_;
  for (int y = 0; y < Y; y++) {
    float w = wb[(size_t)y * sy];
    if (w != 0.f) {
      const float* r = vb + (size_t)y * D_;
      a0 += w * r[t]; a1 += w * r[t + 256]; a2 += w * r[t + 512];
    }
  }
  float* o = Om + ((size_t)b * gridDim.x + x) * D_;
  o[t] = a0; o[t + 256] = a1; o[t + 512] = a2;
}

// ---------------- tb[b,d] = b_ta[d] + sum_k trig[b,k]*W_ta[(D+k)*D + d] ----------------
__global__ void k_tb(const float* __restrict__ trig, const float* __restrict__ W_ta,
                     const float* __restrict__ b_ta, float* __restrict__ tb) {
  int b = blockIdx.y;
  int d = blockIdx.x * 256 + threadIdx.x;
  float acc = b_ta[d];
  for (int k = 0; k < D_; k++) acc += trig[b * D_ + k] * W_ta[(size_t)(D_ + k) * D_ + d];
  tb[b * D_ + d] = acc;
}

// ---------------- GEMM, grid-z job select, 32x64 tile, single-buffer+reg prefetch ------
// phase 0: z=0 entn(e0*Wta0 + e0t*Wta2, epilogue +tb,*ne)  z=1 PeA(e0*W1_0 + Ah2h*W1_3)
//          z=2 PaA(argm*W1_1 + Au2u*W1_5)
// phase 1: z=0 PeC(tokA*W1_2)   z=1 PaC(argTok*W1_4)
__global__ __launch_bounds__(256) void k_gemmz(
    int phase, const float* __restrict__ e0, const float* __restrict__ e0t,
    const float* __restrict__ Ah2h, const float* __restrict__ argm,
    const float* __restrict__ Au2u, const float* __restrict__ tokA,
    const float* __restrict__ argTok, const float* __restrict__ W_ta,
    const float* __restrict__ W1, float* __restrict__ entn, float* __restrict__ PeA,
    float* __restrict__ PaA, float* __restrict__ PeC, float* __restrict__ PaC,
    const float* __restrict__ tb, const float* __restrict__ ne) {
  int z = blockIdx.z;
  const float *A0, *B0, *A1, *B1;
  float* C;
  int N, mtiles, np, ep = 0;
  if (phase == 0) {
    if (z == 0) {
      A0 = e0; B0 = W_ta; A1 = e0t; B1 = W_ta + (size_t)2 * D_ * D_;
      C = entn; N = D_; mtiles = 32; np = 2; ep = 1;
    } else if (z == 1) {
      A0 = e0; B0 = W1; A1 = Ah2h; B1 = W1 + (size_t)3 * D_ * NHID_;
      C = PeA; N = NHID_; mtiles = 32; np = 2;
    } else {
      A0 = argm; B0 = W1 + (size_t)D_ * NHID_; A1 = Au2u; B1 = W1 + (size_t)5 * D_ * NHID_;
      C = PaA; N = NHID_; mtiles = 16; np = 2;
    }
  } else {
    if (z == 0) {
      A0 = tokA; B0 = W1 + (size_t)2 * D_ * NHID_; A1 = A0; B1 = B0;
      C = PeC; N = NHID_; mtiles = 32; np = 1;
    } else {
      A0 = argTok; B0 = W1 + (size_t)4 * D_ * NHID_; A1 = A0; B1 = B0;
      C = PaC; N = NHID_; mtiles = 16; np = 1;
    }
  }
  int bx = blockIdx.x, by = blockIdx.y;
  if (by >= mtiles || bx * 64 >= N) return;  // uniform early exit, before any barrier

  __shared__ float As[32][17];
  __shared__ float Bs[16][68];
  int tid = threadIdx.x;
  int arow = tid >> 3, acol = (tid & 7) << 1;
  int brow = tid >> 4, bcol = (tid & 15) << 2;
  int tx = tid & 15, ty = tid >> 4;

  const float* aBase0 = A0 + (size_t)(by * 32 + arow) * D_ + acol;
  const float* aBase1 = A1 + (size_t)(by * 32 + arow) * D_ + acol;
  const float* bBase0 = B0 + (size_t)brow * N + bx * 64 + bcol;
  const float* bBase1 = B1 + (size_t)brow * N + bx * 64 + bcol;

  float2 av = *(const float2*)aBase0;
  float4 bv = *(const float4*)bBase0;
  float acc[2][4] = {};
  int niter = np * 48;
  for (int it = 0; it < niter; ++it) {
    __syncthreads();
    As[arow][acol] = av.x;
    As[arow][acol + 1] = av.y;
    *(float4*)&Bs[brow][bcol] = bv;
    __syncthreads();
    if (it + 1 < niter) {
      int l = it + 1;
      int p = (l >= 48) ? 1 : 0;
      int kk = l - (p ? 48 : 0);
      av = *(const float2*)((p ? aBase1 : aBase0) + kk * 16);
      bv = *(const float4*)((p ? bBase1 : bBase0) + (size_t)kk * 16 * N);
    }
#pragma unroll
    for (int k = 0; k < 16; ++k) {
      float a0v = As[ty * 2 + 0][k];
      float a1v = As[ty * 2 + 1][k];
      float4 b4 = *(const float4*)&Bs[k][tx * 4];
      acc[0][0] += a0v * b4.x; acc[0][1] += a0v * b4.y;
      acc[0][2] += a0v * b4.z; acc[0][3] += a0v * b4.w;
      acc[1][0] += a1v * b4.x; acc[1][1] += a1v * b4.y;
      acc[1][2] += a1v * b4.z; acc[1][3] += a1v * b4.w;
    }
  }
#pragma unroll
  for (int i = 0; i < 2; ++i) {
    int r = by * 32 + ty * 2 + i;
    int col = bx * 64 + tx * 4;
    float4 v = make_float4(acc[i][0], acc[i][1], acc[i][2], acc[i][3]);
    if (ep) {
      int b = r >> 6;
      float m = ne[r];
      const float* tbr = tb + (size_t)b * D_ + col;
      v.x = (v.x + tbr[0]) * m; v.y = (v.y + tbr[1]) * m;
      v.z = (v.z + tbr[2]) * m; v.w = (v.w + tbr[3]) * m;
    }
    *(float4*)(C + (size_t)r * N + col) = v;
  }
}

// ---------------- score[b,e,a] = dot(entity_new[b,e], arg[b,a]) / sqrt(D) ----------------
__global__ __launch_bounds__(256) void k_score(const float* __restrict__ entn,
                                               const float* __restrict__ argm,
                                               float* __restrict__ score) {
  int b = blockIdx.y, e = blockIdx.x, t = threadIdx.x;
  __shared__ float ent[D_];
  const float* er = entn + ((size_t)b * E_ + e) * D_;
  for (int d = t; d < D_; d += 256) ent[d] = er[d];
  __syncthreads();
  int wave = t >> 6, lane = t & 63;
  const float scale = 0.03608439182435161f;  // 1/sqrt(768)
  for (int a = wave; a < NA_; a += 4) {
    const float* ar = argm + ((size_t)b * NA_ + a) * D_;
    float p = 0.f;
#pragma unroll
    for (int i = 0; i < 12; i++) {
      int d = lane + 64 * i;
      p += ent[d] * ar[d];
    }
    for (int off = 32; off > 0; off >>= 1) p += __shfl_down(p, off);
    if (lane == 0) score[((size_t)b * E_ + e) * NA_ + a] = p * scale;
  }
}

// ---------------- L1 normalize over a (t2a) and over e (a2t) ----------------
__global__ void k_norm(const float* __restrict__ score, float* __restrict__ t2a,
                       float* __restrict__ a2t) {
  int b = blockIdx.x, t = threadIdx.x;
  __shared__ float s[E_ * NA_];
  __shared__ float rs[E_];
  __shared__ float cs[NA_];
  for (int i = t; i < E_ * NA_; i += 256) s[i] = score[(size_t)b * E_ * NA_ + i];
  __syncthreads();
  if (t < E_) {
    float sum = 0.f;
    for (int a = 0; a < NA_; a++) sum += fabsf(s[t * NA_ + a]);
    rs[t] = fmaxf(sum, EPSF);
  } else if (t >= 64 && t < 96) {
    int a = t - 64;
    float sum = 0.f;
    for (int e = 0; e < E_; e++) sum += fabsf(s[e * NA_ + a]);
    cs[a] = fmaxf(sum, EPSF);
  }
  __syncthreads();
  for (int i = t; i < E_ * NA_; i += 256) {
    int e = i >> 5, a = i & 31;
    float v = s[i];
    t2a[(size_t)b * E_ * NA_ + i] = v / rs[e];
    a2t[(size_t)b * E_ * NA_ + i] = v / cs[a];
  }
}

// ---------------- a2a = softmax(arg @ arg^T) ----------------
__global__ __launch_bounds__(256) void k_a2a(const float* __restrict__ argm,
                                             float* __restrict__ a2a) {
  int b = blockIdx.y, a = blockIdx.x, t = threadIdx.x;
  __shared__ float sA[D_];
  __shared__ float lg[NA_];
  const float* ar = argm + ((size_t)b * NA_ + a) * D_;
  for (int d = t; d < D_; d += 256) sA[d] = ar[d];
  __syncthreads();
  int wave = t >> 6, lane = t & 63;
  for (int a2 = wave; a2 < NA_; a2 += 4) {
    const float* br = argm + ((size_t)b * NA_ + a2) * D_;
    float p = 0.f;
#pragma unroll
    for (int i = 0; i < 12; i++) {
      int d = lane + 64 * i;
      p += sA[d] * br[d];
    }
    for (int off = 32; off > 0; off >>= 1) p += __shfl_down(p, off);
    if (lane == 0) lg[a2] = p;
  }
  __syncthreads();
  if (t < 64) {
    float v = (t < NA_) ? lg[t] : -INFINITY;
    float m = v;
    for (int mask = 16; mask > 0; mask >>= 1) m = fmaxf(m, __shfl_xor(m, mask));
    float ex = (t < NA_) ? expf(v - m) : 0.f;
    float sm = ex;
    for (int mask = 16; mask > 0; mask >>= 1) sm += __shfl_xor(sm, mask);
    if (t < NA_) a2a[((size_t)b * NA_ + a) * NA_ + t] = ex / sm;
  }
}

// ---------------- t2t: gathered, head-mean, per-att row-normalized, averaged ----------------
__global__ __launch_bounds__(128) void k_t2t(const float* __restrict__ att0,
                                             const float* __restrict__ att1,
                                             const float* __restrict__ att2,
                                             const int* __restrict__ idxs,
                                             const int* __restrict__ meta,
                                             float* __restrict__ t2t) {
  int b = blockIdx.y, s = blockIdx.x, t = threadIdx.x;
  int sb = meta[b * 4 + 0];
  float* out = t2t + ((size_t)b * S_ + s) * S_;
  if (s >= sb) {
    for (int j = t; j < S_; j += 128) out[j] = 0.f;
    return;
  }
  int Is = idxs[b * WIDX_ + s];
  int It = (t < S_) ? idxs[b * WIDX_ + t] : 0;
  __shared__ float row[256];
  __shared__ float red[128];
  const float* atts[3] = {att0, att1, att2};
  float accout = 0.f;
  for (int q = 0; q < 3; q++) {
    float r0 = 0.f, r1 = 0.f;
    const float* base = atts[q] + (((size_t)b * H_) * L_ + Is) * L_;
    for (int h = 0; h < H_; h++) {
      const float* rp = base + (size_t)h * L_ * L_;
      r0 += rp[t];
      r1 += rp[t + 128];
    }
    row[t] = r0;
    row[t + 128] = r1;
    __syncthreads();
    float v = (t < sb) ? row[It] * (1.f / 12.f) : 0.f;
    red[t] = v;
    __syncthreads();
    for (int s2 = 64; s2 > 0; s2 >>= 1) {
      if (t < s2) red[t] += red[t + s2];
      __syncthreads();
    }
    float rsum = red[0];
    __syncthreads();
    accout += v / fmaxf(rsum, EPSF) * (1.f / 3.f);
  }
  if (t < S_) out[t] = accout;
}

// ---------------- final: out = gelu(PeA+PeC + PaA+PaC + b1) @ W2 + b2 ----------------
__global__ __launch_bounds__(256) void k_final(const float* __restrict__ PeA,
                                               const float* __restrict__ PeC,
                                               const float* __restrict__ PaA,
                                               const float* __restrict__ PaC,
                                               const float* __restrict__ b1,
                                               const float* __restrict__ W2,
                                               const float* __restrict__ b2,
                                               float* __restrict__ out) {
  int b = blockIdx.y, e = blockIdx.x, t = threadIdx.x;
  __shared__ float pe[NHID_];
  size_t po = ((size_t)b * E_ + e) * NHID_;
  for (int n = t; n < NHID_; n += 256) pe[n] = PeA[po + n] + PeC[po + n] + b1[n];
  __syncthreads();
  int a = t >> 3, c = t & 7;
  size_t ao = ((size_t)b * NA_ + a) * NHID_;
  const float* parA = PaA + ao;
  const float* parC = PaC + ao;
  float acc = 0.f;
#pragma unroll 4
  for (int jj = 0; jj < 128; ++jj) {
    int n = c * 128 + jj;
    float x = pe[n] + parA[n] + parC[n];
    float g = 0.5f * x * (1.f + erff(x * 0.70710678118654752f));
    acc += g * W2[n];
  }
  acc += __shfl_down(acc, 4);
  acc += __shfl_down(acc, 2);
  acc += __shfl_down(acc, 1);
  if (c == 0) out[((size_t)b * E_ + e) * NA_ + a] = acc + b2[0];
}

extern "C" void kernel_launch(void* const* d_in, const int* in_sizes, int n_in,
                              void* d_out, int out_size, void* d_ws, size_t ws_size,
                              hipStream_t stream) {
  const float* emb    = (const float*)d_in[0];
  const float* istrig = (const float*)d_in[1];
  const float* argw   = (const float*)d_in[2];
  const float* entmap = (const float*)d_in[3];
  const float* att0   = (const float*)d_in[4];
  const float* att1   = (const float*)d_in[5];
  const float* att2   = (const float*)d_in[6];
  const float* W_ta   = (const float*)d_in[7];
  const float* b_ta   = (const float*)d_in[8];
  const float* W1     = (const float*)d_in[9];
  const float* b1     = (const float*)d_in[10];
  const float* W2     = (const float*)d_in[11];
  const float* b2     = (const float*)d_in[12];
  const int*   idxs   = (const int*)d_in[13];
  const int*   blen   = (const int*)d_in[14];
  float* out = (float*)d_out;

  float* ws = (float*)d_ws;
  size_t o = 0;
  int* meta = (int*)ws; o += 256;
  float* sent_emb = ws + o; o += (size_t)B_ * S_ * D_;   // dead after phase A -> reused as PeC
  float* arg_emb  = ws + o; o += (size_t)B_ * LA_ * D_;  // dead after argm  -> reused as PaC
  float* trig     = ws + o; o += (size_t)B_ * D_;
  float* e0       = ws + o; o += (size_t)B_ * E_ * D_;
  float* e0t      = ws + o; o += (size_t)B_ * E_ * D_;
  float* argm     = ws + o; o += (size_t)B_ * NA_ * D_;
  float* entn     = ws + o; o += (size_t)B_ * E_ * D_;
  float* tb       = ws + o; o += (size_t)B_ * D_;
  float* ne       = ws + o; o += (size_t)B_ * E_;
  float* score    = ws + o; o += (size_t)B_ * E_ * NA_;
  float* t2a      = ws + o; o += (size_t)B_ * E_ * NA_;
  float* a2t      = ws + o; o += (size_t)B_ * E_ * NA_;
  float* t2t      = ws + o; o += (size_t)B_ * S_ * S_;
  float* ah2h     = ws + o; o += (size_t)B_ * S_ * D_;
  float* Ah2h     = ws + o; o += (size_t)B_ * E_ * D_;
  float* tokA     = ws + o; o += (size_t)B_ * E_ * D_;
  float* argTok   = ws + o; o += (size_t)B_ * NA_ * D_;
  float* a2a      = ws + o; o += (size_t)B_ * NA_ * NA_;
  float* Au2u     = ws + o; o += (size_t)B_ * NA_ * D_;
  float* PeA      = ws + o; o += (size_t)B_ * E_ * NHID_;
  float* PaA      = ws + o; o += (size_t)B_ * NA_ * NHID_;
  // phase-D outputs overlap buffers that are dead by then:
  float* PeC = sent_emb;  // 1.05M floats <= 1.23M
  float* PaC = arg_emb;   // 0.52M floats <= 0.59M

  // ---- phase A: gathers + everything not depending on entity_new ----
  k_meta<<<B_, 128, 0, stream>>>(idxs, blen, meta);
  k_gather<<<dim3(S_ + LA_, B_), 256, 0, stream>>>(emb, idxs, meta, sent_emb, arg_emb);
  k_trig<<<dim3(3, B_), 256, 0, stream>>>(sent_emb, istrig, trig);
  k_entity0<<<dim3(E_, B_), 256, 0, stream>>>(sent_emb, entmap, trig, e0, e0t, ne);
  k_wsum<<<dim3(NA_, B_), 256, 0, stream>>>(argw, LA_ * NA_, NA_, 1, arg_emb, argm, LA_);
  k_tb<<<dim3(3, B_), 256, 0, stream>>>(trig, W_ta, b_ta, tb);
  k_t2t<<<dim3(S_, B_), 128, 0, stream>>>(att0, att1, att2, idxs, meta, t2t);
  k_wsum<<<dim3(S_, B_), 256, 0, stream>>>(t2t, S_ * S_, 1, S_, sent_emb, ah2h, S_);
  k_wsum<<<dim3(E_, B_), 256, 0, stream>>>(entmap, S_ * E_, E_, 1, ah2h, Ah2h, S_);
  k_a2a<<<dim3(NA_, B_), 256, 0, stream>>>(argm, a2a);
  k_wsum<<<dim3(NA_, B_), 256, 0, stream>>>(a2a, NA_ * NA_, 1, NA_, argm, Au2u, NA_);

  // ---- phase B: entn (fused epilogue), PeA, PaA — one launch, 1536-block grid ----
  k_gemmz<<<dim3(16, 32, 3), 256, 0, stream>>>(0, e0, e0t, Ah2h, argm, Au2u, tokA, argTok,
                                               W_ta, W1, entn, PeA, PaA, PeC, PaC, tb, ne);

  // ---- phase C: score path ----
  k_score<<<dim3(E_, B_), 256, 0, stream>>>(entn, argm, score);
  k_norm<<<B_, 256, 0, stream>>>(score, t2a, a2t);
  k_wsum<<<dim3(E_, B_), 256, 0, stream>>>(t2a, E_ * NA_, 1, NA_, argm, tokA, NA_);
  k_wsum<<<dim3(NA_, B_), 256, 0, stream>>>(a2t, E_ * NA_, NA_, 1, entn, argTok, E_);

  // ---- phase D: PeC (tokA), PaC (argTok) — one launch ----
  k_gemmz<<<dim3(16, 32, 2), 256, 0, stream>>>(1, e0, e0t, Ah2h, argm, Au2u, tokA, argTok,
                                               W_ta, W1, entn, PeA, PaA, PeC, PaC, tb, ne);

  // ---- final ----
  k_final<<<dim3(E_, B_), 256, 0, stream>>>(PeA, PeC, PaA, PaC, b1, W2, b2, out);
}

// Round 5
// 761.179 us; speedup vs baseline: 3.8977x; 1.1902x over previous
//
#include <hip/hip_runtime.h>
#include <math.h>

#define B_ 16
#define L_ 256
#define S_ 100
#define LA_ 48
#define NA_ 32
#define E_ 64
#define D_ 768
#define H_ 12
#define NHID_ 1024
#define WIDX_ 102
#define EPSF 1e-12f

// ---------------- meta: per-b sb, sls, last ----------------
__global__ void k_meta(const int* __restrict__ idxs, const int* __restrict__ blen,
                       int* __restrict__ meta) {
  int b = blockIdx.x, t = threadIdx.x;
  __shared__ int cnt;
  if (t == 0) cnt = 0;
  __syncthreads();
  if (t < WIDX_ && idxs[b * WIDX_ + t] > 0) atomicAdd(&cnt, 1);
  __syncthreads();
  if (t == 0) {
    int sb = cnt - 2;
    meta[b * 4 + 0] = sb;
    meta[b * 4 + 1] = idxs[b * WIDX_ + sb];  // sls
    meta[b * 4 + 2] = blen[b] - 1;           // last
  }
}

// ---------------- gather sent_emb (y<S) and arg_emb (y>=S) ----------------
__global__ void k_gather(const float* __restrict__ emb, const int* __restrict__ idxs,
                         const int* __restrict__ meta, float* __restrict__ sent_emb,
                         float* __restrict__ arg_emb) {
  int b = blockIdx.y, y = blockIdx.x, t = threadIdx.x;
  int sb = meta[b * 4 + 0], sls = meta[b * 4 + 1], last = meta[b * 4 + 2];
  if (y < S_) {
    int s = y;
    float* dst = sent_emb + ((size_t)b * S_ + s) * D_;
    if (s < sb) {
      const float* src = emb + ((size_t)b * L_ + idxs[b * WIDX_ + s]) * D_;
      for (int d = t; d < D_; d += 256) dst[d] = src[d];
    } else {
      for (int d = t; d < D_; d += 256) dst[d] = 0.f;
    }
  } else {
    int l = y - S_;
    int pos = sls + 1 + l;
    float* dst = arg_emb + ((size_t)b * LA_ + l) * D_;
    if (pos < last) {
      int p = pos > (L_ - 1) ? (L_ - 1) : pos;
      const float* src = emb + ((size_t)b * L_ + p) * D_;
      for (int d = t; d < D_; d += 256) dst[d] = src[d];
    } else {
      for (int d = t; d < D_; d += 256) dst[d] = 0.f;
    }
  }
}

// ---------------- trig: weighted mean over triggers ----------------
__global__ void k_trig(const float* __restrict__ sent_emb, const float* __restrict__ is_trig,
                       float* __restrict__ trig) {
  int b = blockIdx.y;
  int d = blockIdx.x * 256 + threadIdx.x;
  float acc = 0.f, den = 0.f;
  for (int s = 0; s < S_; s++) {
    float w = is_trig[b * S_ + s];
    den += w;
    if (w != 0.f) acc += w * sent_emb[((size_t)b * S_ + s) * D_ + d];
  }
  trig[b * D_ + d] = acc / den;
}

// ---------------- entity0 = ent_map^T @ sent_emb ; also e0*trig and nonempty ----------------
__global__ __launch_bounds__(256) void k_entity0(const float* __restrict__ sent_emb,
                                                 const float* __restrict__ ent_map,
                                                 const float* __restrict__ trig,
                                                 float* __restrict__ e0, float* __restrict__ e0t,
                                                 float* __restrict__ ne) {
  int b = blockIdx.y, e = blockIdx.x, t = threadIdx.x;
  float a0 = 0.f, a1 = 0.f, a2 = 0.f;
  for (int s = 0; s < S_; s++) {
    float w = ent_map[((size_t)b * S_ + s) * E_ + e];
    if (w != 0.f) {
      const float* r = sent_emb + ((size_t)b * S_ + s) * D_;
      a0 += w * r[t]; a1 += w * r[t + 256]; a2 += w * r[t + 512];
    }
  }
  size_t o = ((size_t)b * E_ + e) * D_;
  e0[o + t] = a0; e0[o + t + 256] = a1; e0[o + t + 512] = a2;
  const float* tr = trig + b * D_;
  e0t[o + t] = a0 * tr[t];
  e0t[o + t + 256] = a1 * tr[t + 256];
  e0t[o + t + 512] = a2 * tr[t + 512];
  __shared__ float red[256];
  red[t] = fabsf(a0) + fabsf(a1) + fabsf(a2);
  __syncthreads();
  for (int s2 = 128; s2 > 0; s2 >>= 1) {
    if (t < s2) red[t] += red[t + s2];
    __syncthreads();
  }
  if (t == 0) ne[b * E_ + e] = (red[0] > 0.f) ? 1.f : 0.f;
}

// ---------------- generic weighted sum: O[b,x,:] = sum_y W[b, y*sy + x*sx] * V[b,y,:] ----------------
__global__ __launch_bounds__(256) void k_wsum(const float* __restrict__ Wm, int wstride, int sy,
                                              int sx, const float* __restrict__ Vm,
                                              float* __restrict__ Om, int Y) {
  int b = blockIdx.y, x = blockIdx.x, t = threadIdx.x;
  float a0 = 0.f, a1 = 0.f, a2 = 0.f;
  const float* wb = Wm + (size_t)b * wstride + (size_t)x * sx;
  const float* vb = Vm + (size_t)b * Y * D_;
  for (int y = 0; y < Y; y++) {
    float w = wb[(size_t)y * sy];
    if (w != 0.f) {
      const float* r = vb + (size_t)y * D_;
      a0 += w * r[t]; a1 += w * r[t + 256]; a2 += w * r[t + 512];
    }
  }
  float* o = Om + ((size_t)b * gridDim.x + x) * D_;
  o[t] = a0; o[t + 256] = a1; o[t + 512] = a2;
}

// ---------------- tb[b,d] = b_ta[d] + sum_k trig[b,k]*W_ta[(D+k)*D + d] ----------------
__global__ void k_tb(const float* __restrict__ trig, const float* __restrict__ W_ta,
                     const float* __restrict__ b_ta, float* __restrict__ tb) {
  int b = blockIdx.y;
  int d = blockIdx.x * 256 + threadIdx.x;
  float acc0 = b_ta[d], acc1 = 0.f, acc2 = 0.f, acc3 = 0.f;
  float acc4 = 0.f, acc5 = 0.f, acc6 = 0.f, acc7 = 0.f;
  const float* tr = trig + b * D_;
  const float* w = W_ta + (size_t)D_ * D_ + d;
  for (int k = 0; k < D_; k += 8) {
    acc0 += tr[k + 0] * w[(size_t)(k + 0) * D_];
    acc1 += tr[k + 1] * w[(size_t)(k + 1) * D_];
    acc2 += tr[k + 2] * w[(size_t)(k + 2) * D_];
    acc3 += tr[k + 3] * w[(size_t)(k + 3) * D_];
    acc4 += tr[k + 4] * w[(size_t)(k + 4) * D_];
    acc5 += tr[k + 5] * w[(size_t)(k + 5) * D_];
    acc6 += tr[k + 6] * w[(size_t)(k + 6) * D_];
    acc7 += tr[k + 7] * w[(size_t)(k + 7) * D_];
  }
  tb[b * D_ + d] = ((acc0 + acc1) + (acc2 + acc3)) + ((acc4 + acc5) + (acc6 + acc7));
}

// ---------------- GEMM, grid-z job select, 32x64 tile, single-buffer+reg prefetch ------
__global__ __launch_bounds__(256) void k_gemmz(
    int phase, const float* __restrict__ e0, const float* __restrict__ e0t,
    const float* __restrict__ Ah2h, const float* __restrict__ argm,
    const float* __restrict__ Au2u, const float* __restrict__ tokA,
    const float* __restrict__ argTok, const float* __restrict__ W_ta,
    const float* __restrict__ W1, float* __restrict__ entn, float* __restrict__ PeA,
    float* __restrict__ PaA, float* __restrict__ PeC, float* __restrict__ PaC,
    const float* __restrict__ tb, const float* __restrict__ ne) {
  int z = blockIdx.z;
  const float *A0, *B0, *A1, *B1;
  float* C;
  int N, mtiles, np, ep = 0;
  if (phase == 0) {
    if (z == 0) {
      A0 = e0; B0 = W_ta; A1 = e0t; B1 = W_ta + (size_t)2 * D_ * D_;
      C = entn; N = D_; mtiles = 32; np = 2; ep = 1;
    } else if (z == 1) {
      A0 = e0; B0 = W1; A1 = Ah2h; B1 = W1 + (size_t)3 * D_ * NHID_;
      C = PeA; N = NHID_; mtiles = 32; np = 2;
    } else {
      A0 = argm; B0 = W1 + (size_t)D_ * NHID_; A1 = Au2u; B1 = W1 + (size_t)5 * D_ * NHID_;
      C = PaA; N = NHID_; mtiles = 16; np = 2;
    }
  } else {
    if (z == 0) {
      A0 = tokA; B0 = W1 + (size_t)2 * D_ * NHID_; A1 = A0; B1 = B0;
      C = PeC; N = NHID_; mtiles = 32; np = 1;
    } else {
      A0 = argTok; B0 = W1 + (size_t)4 * D_ * NHID_; A1 = A0; B1 = B0;
      C = PaC; N = NHID_; mtiles = 16; np = 1;
    }
  }
  int bx = blockIdx.x, by = blockIdx.y;
  if (by >= mtiles || bx * 64 >= N) return;  // uniform early exit, before any barrier

  __shared__ float As[32][17];
  __shared__ float Bs[16][68];
  int tid = threadIdx.x;
  int arow = tid >> 3, acol = (tid & 7) << 1;
  int brow = tid >> 4, bcol = (tid & 15) << 2;
  int tx = tid & 15, ty = tid >> 4;

  const float* aBase0 = A0 + (size_t)(by * 32 + arow) * D_ + acol;
  const float* aBase1 = A1 + (size_t)(by * 32 + arow) * D_ + acol;
  const float* bBase0 = B0 + (size_t)brow * N + bx * 64 + bcol;
  const float* bBase1 = B1 + (size_t)brow * N + bx * 64 + bcol;

  float2 av = *(const float2*)aBase0;
  float4 bv = *(const float4*)bBase0;
  float acc[2][4] = {};
  int niter = np * 48;
  for (int it = 0; it < niter; ++it) {
    __syncthreads();
    As[arow][acol] = av.x;
    As[arow][acol + 1] = av.y;
    *(float4*)&Bs[brow][bcol] = bv;
    __syncthreads();
    if (it + 1 < niter) {
      int l = it + 1;
      int p = (l >= 48) ? 1 : 0;
      int kk = l - (p ? 48 : 0);
      av = *(const float2*)((p ? aBase1 : aBase0) + kk * 16);
      bv = *(const float4*)((p ? bBase1 : bBase0) + (size_t)kk * 16 * N);
    }
#pragma unroll
    for (int k = 0; k < 16; ++k) {
      float a0v = As[ty * 2 + 0][k];
      float a1v = As[ty * 2 + 1][k];
      float4 b4 = *(const float4*)&Bs[k][tx * 4];
      acc[0][0] += a0v * b4.x; acc[0][1] += a0v * b4.y;
      acc[0][2] += a0v * b4.z; acc[0][3] += a0v * b4.w;
      acc[1][0] += a1v * b4.x; acc[1][1] += a1v * b4.y;
      acc[1][2] += a1v * b4.z; acc[1][3] += a1v * b4.w;
    }
  }
#pragma unroll
  for (int i = 0; i < 2; ++i) {
    int r = by * 32 + ty * 2 + i;
    int col = bx * 64 + tx * 4;
    float4 v = make_float4(acc[i][0], acc[i][1], acc[i][2], acc[i][3]);
    if (ep) {
      int b = r >> 6;
      float m = ne[r];
      const float* tbr = tb + (size_t)b * D_ + col;
      v.x = (v.x + tbr[0]) * m; v.y = (v.y + tbr[1]) * m;
      v.z = (v.z + tbr[2]) * m; v.w = (v.w + tbr[3]) * m;
    }
    *(float4*)(C + (size_t)r * N + col) = v;
  }
}

// ---------------- score[b,e,a] = dot(entity_new[b,e], arg[b,a]) / sqrt(D) ----------------
__global__ __launch_bounds__(256) void k_score(const float* __restrict__ entn,
                                               const float* __restrict__ argm,
                                               float* __restrict__ score) {
  int b = blockIdx.y, e = blockIdx.x, t = threadIdx.x;
  __shared__ float ent[D_];
  const float* er = entn + ((size_t)b * E_ + e) * D_;
  for (int d = t; d < D_; d += 256) ent[d] = er[d];
  __syncthreads();
  int wave = t >> 6, lane = t & 63;
  const float scale = 0.03608439182435161f;  // 1/sqrt(768)
  for (int a = wave; a < NA_; a += 4) {
    const float* ar = argm + ((size_t)b * NA_ + a) * D_;
    float p = 0.f;
#pragma unroll
    for (int i = 0; i < 12; i++) {
      int d = lane + 64 * i;
      p += ent[d] * ar[d];
    }
    for (int off = 32; off > 0; off >>= 1) p += __shfl_down(p, off);
    if (lane == 0) score[((size_t)b * E_ + e) * NA_ + a] = p * scale;
  }
}

// ---------------- L1 normalize over a (t2a) and over e (a2t) ----------------
__global__ void k_norm(const float* __restrict__ score, float* __restrict__ t2a,
                       float* __restrict__ a2t) {
  int b = blockIdx.x, t = threadIdx.x;
  __shared__ float s[E_ * NA_];
  __shared__ float rs[E_];
  __shared__ float cs[NA_];
  for (int i = t; i < E_ * NA_; i += 256) s[i] = score[(size_t)b * E_ * NA_ + i];
  __syncthreads();
  if (t < E_) {
    float sum = 0.f;
    for (int a = 0; a < NA_; a++) sum += fabsf(s[t * NA_ + a]);
    rs[t] = fmaxf(sum, EPSF);
  } else if (t >= 64 && t < 96) {
    int a = t - 64;
    float sum = 0.f;
    for (int e = 0; e < E_; e++) sum += fabsf(s[e * NA_ + a]);
    cs[a] = fmaxf(sum, EPSF);
  }
  __syncthreads();
  for (int i = t; i < E_ * NA_; i += 256) {
    int e = i >> 5, a = i & 31;
    float v = s[i];
    t2a[(size_t)b * E_ * NA_ + i] = v / rs[e];
    a2t[(size_t)b * E_ * NA_ + i] = v / cs[a];
  }
}

// ---------------- a2a = softmax(arg @ arg^T) ----------------
__global__ __launch_bounds__(256) void k_a2a(const float* __restrict__ argm,
                                             float* __restrict__ a2a) {
  int b = blockIdx.y, a = blockIdx.x, t = threadIdx.x;
  __shared__ float sA[D_];
  __shared__ float lg[NA_];
  const float* ar = argm + ((size_t)b * NA_ + a) * D_;
  for (int d = t; d < D_; d += 256) sA[d] = ar[d];
  __syncthreads();
  int wave = t >> 6, lane = t & 63;
  for (int a2 = wave; a2 < NA_; a2 += 4) {
    const float* br = argm + ((size_t)b * NA_ + a2) * D_;
    float p = 0.f;
#pragma unroll
    for (int i = 0; i < 12; i++) {
      int d = lane + 64 * i;
      p += sA[d] * br[d];
    }
    for (int off = 32; off > 0; off >>= 1) p += __shfl_down(p, off);
    if (lane == 0) lg[a2] = p;
  }
  __syncthreads();
  if (t < 64) {
    float v = (t < NA_) ? lg[t] : -INFINITY;
    float m = v;
    for (int mask = 16; mask > 0; mask >>= 1) m = fmaxf(m, __shfl_xor(m, mask));
    float ex = (t < NA_) ? expf(v - m) : 0.f;
    float sm = ex;
    for (int mask = 16; mask > 0; mask >>= 1) sm += __shfl_xor(sm, mask);
    if (t < NA_) a2a[((size_t)b * NA_ + a) * NA_ + t] = ex / sm;
  }
}

// ---------------- t2t: gathered, head-mean, per-att row-normalized, averaged ----------------
__global__ __launch_bounds__(128) void k_t2t(const float* __restrict__ att0,
                                             const float* __restrict__ att1,
                                             const float* __restrict__ att2,
                                             const int* __restrict__ idxs,
                                             const int* __restrict__ meta,
                                             float* __restrict__ t2t) {
  int b = blockIdx.y, s = blockIdx.x, t = threadIdx.x;
  int sb = meta[b * 4 + 0];
  float* out = t2t + ((size_t)b * S_ + s) * S_;
  if (s >= sb) {
    for (int j = t; j < S_; j += 128) out[j] = 0.f;
    return;
  }
  int Is = idxs[b * WIDX_ + s];
  int It = (t < S_) ? idxs[b * WIDX_ + t] : 0;
  __shared__ float row[256];
  __shared__ float red[128];
  const float* atts[3] = {att0, att1, att2};
  float accout = 0.f;
  for (int q = 0; q < 3; q++) {
    float r0 = 0.f, r1 = 0.f;
    const float* base = atts[q] + (((size_t)b * H_) * L_ + Is) * L_;
    for (int h = 0; h < H_; h++) {
      const float* rp = base + (size_t)h * L_ * L_;
      r0 += rp[t];
      r1 += rp[t + 128];
    }
    row[t] = r0;
    row[t + 128] = r1;
    __syncthreads();
    float v = (t < sb) ? row[It] * (1.f / 12.f) : 0.f;
    red[t] = v;
    __syncthreads();
    for (int s2 = 64; s2 > 0; s2 >>= 1) {
      if (t < s2) red[t] += red[t + s2];
      __syncthreads();
    }
    float rsum = red[0];
    __syncthreads();
    accout += v / fmaxf(rsum, EPSF) * (1.f / 3.f);
  }
  if (t < S_) out[t] = accout;
}

// ---------------- final: out = gelu(PeA+PeC + PaA+PaC + b1) @ W2 + b2 ----------------
// thread t owns n in [4t,4t+4) in registers; loops all 32 a with coalesced float4
// reads; 32 accumulators; wave butterfly + tiny LDS cross-wave reduce. No LDS in
// main loop (R4 had 8-way bank conflicts on the pe[] tile: 7.3M SQ_LDS_BANK_CONFLICT).
__global__ __launch_bounds__(256) void k_final(const float* __restrict__ PeA,
                                               const float* __restrict__ PeC,
                                               const float* __restrict__ PaA,
                                               const float* __restrict__ PaC,
                                               const float* __restrict__ b1,
                                               const float* __restrict__ W2,
                                               const float* __restrict__ b2,
                                               float* __restrict__ out) {
  int b = blockIdx.y, e = blockIdx.x, t = threadIdx.x;
  size_t po = ((size_t)b * E_ + e) * NHID_;
  int n0 = t * 4;
  float4 pA = *(const float4*)(PeA + po + n0);
  float4 pC = *(const float4*)(PeC + po + n0);
  float4 bb = *(const float4*)(b1 + n0);
  float4 pe4 = make_float4(pA.x + pC.x + bb.x, pA.y + pC.y + bb.y, pA.z + pC.z + bb.z,
                           pA.w + pC.w + bb.w);
  float4 w4 = *(const float4*)(W2 + n0);
  float acc[NA_];
  const float ks = 0.70710678118654752f;
#pragma unroll
  for (int a = 0; a < NA_; ++a) {
    size_t ao = ((size_t)b * NA_ + a) * NHID_ + n0;
    float4 qA = *(const float4*)(PaA + ao);
    float4 qC = *(const float4*)(PaC + ao);
    float x0 = pe4.x + qA.x + qC.x;
    float x1 = pe4.y + qA.y + qC.y;
    float x2 = pe4.z + qA.z + qC.z;
    float x3 = pe4.w + qA.w + qC.w;
    float g0 = 0.5f * x0 * (1.f + erff(x0 * ks));
    float g1 = 0.5f * x1 * (1.f + erff(x1 * ks));
    float g2 = 0.5f * x2 * (1.f + erff(x2 * ks));
    float g3 = 0.5f * x3 * (1.f + erff(x3 * ks));
    acc[a] = g0 * w4.x + g1 * w4.y + g2 * w4.z + g3 * w4.w;
  }
  // full-wave butterfly: every lane ends with the wave sum for each a
#pragma unroll
  for (int a = 0; a < NA_; ++a) {
    float v = acc[a];
    v += __shfl_xor(v, 32);
    v += __shfl_xor(v, 16);
    v += __shfl_xor(v, 8);
    v += __shfl_xor(v, 4);
    v += __shfl_xor(v, 2);
    v += __shfl_xor(v, 1);
    acc[a] = v;
  }
  __shared__ float part[4][NA_ + 1];
  int wave = t >> 6, lane = t & 63;
  if (lane < NA_) part[wave][lane] = acc[lane];
  __syncthreads();
  if (t < NA_) {
    float v = part[0][t] + part[1][t] + part[2][t] + part[3][t];
    out[((size_t)b * E_ + e) * NA_ + t] = v + b2[0];
  }
}

extern "C" void kernel_launch(void* const* d_in, const int* in_sizes, int n_in,
                              void* d_out, int out_size, void* d_ws, size_t ws_size,
                              hipStream_t stream) {
  const float* emb    = (const float*)d_in[0];
  const float* istrig = (const float*)d_in[1];
  const float* argw   = (const float*)d_in[2];
  const float* entmap = (const float*)d_in[3];
  const float* att0   = (const float*)d_in[4];
  const float* att1   = (const float*)d_in[5];
  const float* att2   = (const float*)d_in[6];
  const float* W_ta   = (const float*)d_in[7];
  const float* b_ta   = (const float*)d_in[8];
  const float* W1     = (const float*)d_in[9];
  const float* b1     = (const float*)d_in[10];
  const float* W2     = (const float*)d_in[11];
  const float* b2     = (const float*)d_in[12];
  const int*   idxs   = (const int*)d_in[13];
  const int*   blen   = (const int*)d_in[14];
  float* out = (float*)d_out;

  float* ws = (float*)d_ws;
  size_t o = 0;
  int* meta = (int*)ws; o += 256;
  float* sent_emb = ws + o; o += (size_t)B_ * S_ * D_;   // dead after phase A -> reused as PeC
  float* arg_emb  = ws + o; o += (size_t)B_ * LA_ * D_;  // dead after argm  -> reused as PaC
  float* trig     = ws + o; o += (size_t)B_ * D_;
  float* e0       = ws + o; o += (size_t)B_ * E_ * D_;
  float* e0t      = ws + o; o += (size_t)B_ * E_ * D_;
  float* argm     = ws + o; o += (size_t)B_ * NA_ * D_;
  float* entn     = ws + o; o += (size_t)B_ * E_ * D_;
  float* tb       = ws + o; o += (size_t)B_ * D_;
  float* ne       = ws + o; o += (size_t)B_ * E_;
  float* score    = ws + o; o += (size_t)B_ * E_ * NA_;
  float* t2a      = ws + o; o += (size_t)B_ * E_ * NA_;
  float* a2t      = ws + o; o += (size_t)B_ * E_ * NA_;
  float* t2t      = ws + o; o += (size_t)B_ * S_ * S_;
  float* ah2h     = ws + o; o += (size_t)B_ * S_ * D_;
  float* Ah2h     = ws + o; o += (size_t)B_ * E_ * D_;
  float* tokA     = ws + o; o += (size_t)B_ * E_ * D_;
  float* argTok   = ws + o; o += (size_t)B_ * NA_ * D_;
  float* a2a      = ws + o; o += (size_t)B_ * NA_ * NA_;
  float* Au2u     = ws + o; o += (size_t)B_ * NA_ * D_;
  float* PeA      = ws + o; o += (size_t)B_ * E_ * NHID_;
  float* PaA      = ws + o; o += (size_t)B_ * NA_ * NHID_;
  // phase-D outputs overlap buffers that are dead by then:
  float* PeC = sent_emb;  // 1.05M floats <= 1.23M
  float* PaC = arg_emb;   // 0.52M floats <= 0.59M

  // ---- phase A: gathers + everything not depending on entity_new ----
  k_meta<<<B_, 128, 0, stream>>>(idxs, blen, meta);
  k_gather<<<dim3(S_ + LA_, B_), 256, 0, stream>>>(emb, idxs, meta, sent_emb, arg_emb);
  k_trig<<<dim3(3, B_), 256, 0, stream>>>(sent_emb, istrig, trig);
  k_entity0<<<dim3(E_, B_), 256, 0, stream>>>(sent_emb, entmap, trig, e0, e0t, ne);
  k_wsum<<<dim3(NA_, B_), 256, 0, stream>>>(argw, LA_ * NA_, NA_, 1, arg_emb, argm, LA_);
  k_tb<<<dim3(3, B_), 256, 0, stream>>>(trig, W_ta, b_ta, tb);
  k_t2t<<<dim3(S_, B_), 128, 0, stream>>>(att0, att1, att2, idxs, meta, t2t);
  k_wsum<<<dim3(S_, B_), 256, 0, stream>>>(t2t, S_ * S_, 1, S_, sent_emb, ah2h, S_);
  k_wsum<<<dim3(E_, B_), 256, 0, stream>>>(entmap, S_ * E_, E_, 1, ah2h, Ah2h, S_);
  k_a2a<<<dim3(NA_, B_), 256, 0, stream>>>(argm, a2a);
  k_wsum<<<dim3(NA_, B_), 256, 0, stream>>>(a2a, NA_ * NA_, 1, NA_, argm, Au2u, NA_);

  // ---- phase B: entn (fused epilogue), PeA, PaA — one launch, 1536-block grid ----
  k_gemmz<<<dim3(16, 32, 3), 256, 0, stream>>>(0, e0, e0t, Ah2h, argm, Au2u, tokA, argTok,
                                               W_ta, W1, entn, PeA, PaA, PeC, PaC, tb, ne);

  // ---- phase C: score path ----
  k_score<<<dim3(E_, B_), 256, 0, stream>>>(entn, argm, score);
  k_norm<<<B_, 256, 0, stream>>>(score, t2a, a2t);
  k_wsum<<<dim3(E_, B_), 256, 0, stream>>>(t2a, E_ * NA_, 1, NA_, argm, tokA, NA_);
  k_wsum<<<dim3(NA_, B_), 256, 0, stream>>>(a2t, E_ * NA_, NA_, 1, entn, argTok, E_);

  // ---- phase D: PeC (tokA), PaC (argTok) — one launch ----
  k_gemmz<<<dim3(16, 32, 2), 256, 0, stream>>>(1, e0, e0t, Ah2h, argm, Au2u, tokA, argTok,
                                               W_ta, W1, entn, PeA, PaA, PeC, PaC, tb, ne);

  // ---- final ----
  k_final<<<dim3(E_, B_), 256, 0, stream>>>(PeA, PeC, PaA, PaC, b1, W2, b2, out);
}